// Round 1
// baseline (366.321 us; speedup 1.0000x reference)
//
#include <hip/hip_runtime.h>
#include <math.h>

typedef _Float16 f16;
typedef _Float16 f16x8 __attribute__((ext_vector_type(8)));
typedef float f32x4 __attribute__((ext_vector_type(4)));

#define BB 4
#define CC 256
#define CI 128
#define NN 12544
#define MM 1568
#define TP 8
#define HP 14
#define WP 14

// workspace byte offsets (all 16B aligned)
#define OFF_W3T 0u
#define OFF_WWH 196608u
#define OFF_B3  262144u
#define OFF_SC  263168u
#define OFF_OFB 264192u
#define OFF_XT  265216u
#define OFF_TPG (OFF_XT + 25690112u)
#define OFF_PHI (OFF_TPG + 38535168u)
#define OFF_G   (OFF_PHI + 1605632u)
#define OFF_Y   (OFF_G + 1605632u)
#define WS_NEED (OFF_Y + 12845056u)

static __device__ __forceinline__ f32x4 mfma16(f16x8 a, f16x8 b, f32x4 c) {
    return __builtin_amdgcn_mfma_f32_16x16x32_f16(a, b, c, 0, 0, 0);
}

// ---------------- K0a: weight prep ----------------
__global__ __launch_bounds__(256) void k_prep(
    const float* __restrict__ wg, const float* __restrict__ bg,
    const float* __restrict__ wth, const float* __restrict__ bth,
    const float* __restrict__ wph, const float* __restrict__ bph,
    const float* __restrict__ wW, const float* __restrict__ bW,
    const float* __restrict__ gam, const float* __restrict__ bet,
    const float* __restrict__ mean, const float* __restrict__ var,
    f16* __restrict__ w3t, f16* __restrict__ wWh, f16* __restrict__ b3,
    float* __restrict__ sc, float* __restrict__ ofb) {
    int r = blockIdx.x;          // 0..383
    int c = threadIdx.x;         // 0..255
    const float* src = (r < 128) ? (wth + (size_t)r * CC)
                     : (r < 256) ? (wph + (size_t)(r - 128) * CC)
                                 : (wg + (size_t)(r - 256) * CC);
    w3t[(size_t)r * CC + c] = (f16)src[c];
    if (c == 0) {
        float bv = (r < 128) ? bth[r] : (r < 256) ? bph[r - 128] : bg[r - 256];
        b3[r] = (f16)bv;
    }
    if (r < 256) {
        if (c < 128) wWh[(size_t)r * CI + c] = (f16)wW[(size_t)r * CI + c];
        if (c == 0) {
            float s = gam[r] * rsqrtf(var[r] + 1e-5f);
            sc[r] = s;
            ofb[r] = (bW[r] - mean[r]) * s + bet[r];
        }
    }
}

// ---------------- K0b: x (c,n) f32 -> xT (n,c) fp16 ----------------
__global__ __launch_bounds__(256) void k_xt(const float* __restrict__ x, f16* __restrict__ xT) {
    int bid = blockIdx.x;                 // BB*196*4
    int b = bid / (196 * 4); int rem = bid % (196 * 4);
    int nt = rem / 4, ct = rem % 4;
    int n0 = nt * 64, c0 = ct * 64;
    __shared__ float tile[64][65];
    const float* xb = x + (size_t)b * CC * NN;
    for (int p = 0; p < 16; ++p) {
        int idx = p * 256 + threadIdx.x;
        int i = idx >> 6, j = idx & 63;   // i=c-local, j=n-local
        tile[i][j] = xb[(size_t)(c0 + i) * NN + n0 + j];
    }
    __syncthreads();
    f16* xTb = xT + (size_t)b * NN * CC;
    for (int p = 0; p < 16; ++p) {
        int idx = p * 256 + threadIdx.x;
        int n = idx >> 6, c = idx & 63;
        xTb[(size_t)(n0 + n) * CC + c0 + c] = (f16)tile[c][n];
    }
}

// ---------------- K1: fused conv GEMM  tpg[n][0:384] = xT(n,:) @ w3t^T + b3 ----------------
__global__ __launch_bounds__(256) void k_conv(const f16* __restrict__ xT, const f16* __restrict__ w3t,
                                              const f16* __restrict__ b3, f16* __restrict__ tpg) {
    int bid = blockIdx.x;                 // BB*98*3
    int b = bid / (98 * 3); int rem = bid % (98 * 3);
    int nt = rem / 3, ct = rem % 3;
    int n0 = nt * 128, co0 = ct * 128;
    __shared__ f16 As[128 * 64];          // [n][k] swizzled, 64-half rows
    __shared__ f16 Bs[128 * 64];          // [co][k] swizzled
    const f16* xb = xT + (size_t)b * NN * CC + (size_t)n0 * CC;
    const f16* wb = w3t + (size_t)co0 * CC;
    int wv = threadIdx.x >> 6, ln = threadIdx.x & 63;
    int wr = (wv & 1) * 64, wc = (wv >> 1) * 64;
    f32x4 acc[4][4];
    for (int i = 0; i < 4; ++i) for (int j = 0; j < 4; ++j)
        for (int r = 0; r < 4; ++r) acc[i][j][r] = 0.f;
    for (int ks = 0; ks < 4; ++ks) {
        for (int s = threadIdx.x; s < 1024; s += 256) {
            int row = s >> 3, sl = s & 7;
            f16x8 va = *(const f16x8*)(xb + (size_t)row * CC + ks * 64 + sl * 8);
            *(f16x8*)(As + row * 64 + ((sl * 8) ^ ((row & 7) << 3))) = va;
            f16x8 vb = *(const f16x8*)(wb + (size_t)row * CC + ks * 64 + sl * 8);
            *(f16x8*)(Bs + row * 64 + ((sl * 8) ^ ((row & 7) << 3))) = vb;
        }
        __syncthreads();
        for (int kc = 0; kc < 2; ++kc) {
            int klo = kc * 32 + ((ln >> 4) * 8);
            f16x8 af[4], bf[4];
            for (int i = 0; i < 4; ++i) {
                int rn = wr + i * 16 + (ln & 15);
                af[i] = *(const f16x8*)(As + rn * 64 + (klo ^ ((rn & 7) << 3)));
                int rc = wc + i * 16 + (ln & 15);
                bf[i] = *(const f16x8*)(Bs + rc * 64 + (klo ^ ((rc & 7) << 3)));
            }
            for (int i = 0; i < 4; ++i)
                for (int j = 0; j < 4; ++j)
                    acc[i][j] = mfma16(af[i], bf[j], acc[i][j]);
        }
        __syncthreads();
    }
    f16* ob = tpg + (size_t)b * NN * 384 + (size_t)n0 * 384 + co0;
    for (int j = 0; j < 4; ++j) {
        float bias = (float)b3[co0 + wc + j * 16 + (ln & 15)];
        for (int i = 0; i < 4; ++i)
            for (int r = 0; r < 4; ++r) {
                int n = wr + i * 16 + (ln >> 4) * 4 + r;
                int co = wc + j * 16 + (ln & 15);
                ob[(size_t)n * 384 + co] = (f16)(acc[i][j][r] + bias);
            }
    }
}

// ---------------- K2: maxpool -> phi (m,ci), g (ci,m) ----------------
__global__ __launch_bounds__(256) void k_pool(const f16* __restrict__ tpg,
                                              f16* __restrict__ phi, f16* __restrict__ gx) {
    int bid = blockIdx.x;                 // BB*TP*HP
    int b = bid / (TP * HP); int rem = bid % (TP * HP);
    int tp = rem / HP, hp = rem % HP;
    const f16* base = tpg + (size_t)b * NN * 384;
    for (int idx = threadIdx.x; idx < WP * 128; idx += 256) {
        int wp = idx >> 7, ci = idx & 127;
        f16 mp = (f16)(-60000.0f), mg = (f16)(-60000.0f);
        for (int dt = 0; dt < 2; ++dt)
            for (int dh = 0; dh < 2; ++dh)
                for (int dw = 0; dw < 2; ++dw) {
                    int n = (2 * tp + dt) * 784 + (2 * hp + dh) * 28 + (2 * wp + dw);
                    f16 vp = base[(size_t)n * 384 + 128 + ci];
                    f16 vg = base[(size_t)n * 384 + 256 + ci];
                    mp = vp > mp ? vp : mp;
                    mg = vg > mg ? vg : mg;
                }
        int m = tp * 196 + hp * 14 + wp;
        phi[(size_t)b * MM * CI + (size_t)m * CI + ci] = mp;
        gx[(size_t)b * CI * MM + (size_t)ci * MM + m] = mg;
    }
}

// ---------------- K3: flash attention  y(n,ci) = softmax(theta@phi) @ g ----------------
__global__ __launch_bounds__(256) void k_attn(const f16* __restrict__ tpg, const f16* __restrict__ phi,
                                              const f16* __restrict__ gx, f16* __restrict__ y) {
    int bid = blockIdx.x;                 // BB*196
    int b = bid / 196; int nt = bid % 196;
    int n0 = nt * 64;
    __shared__ f16 Bp[64 * 128];          // phi chunk [m][ci], 128-half rows swizzled
    __shared__ f16 Bg[128 * 64];          // g chunk [ci][m], 64-half rows swizzled
    __shared__ f16 Pl[4 * 16 * 64];       // per-wave P [16][64] swizzled
    int wv = threadIdx.x >> 6, ln = threadIdx.x & 63;
    // theta A-fragments (kept in regs for whole kernel)
    f16x8 af[4];
    {
        int n = n0 + wv * 16 + (ln & 15);
        const f16* rowp = tpg + (size_t)b * NN * 384 + (size_t)n * 384;
        for (int kc = 0; kc < 4; ++kc)
            af[kc] = *(const f16x8*)(rowp + kc * 32 + (ln >> 4) * 8);
    }
    f32x4 yac[8];
    for (int i = 0; i < 8; ++i) for (int r = 0; r < 4; ++r) yac[i][r] = 0.f;
    float mrun[4], lrun[4];
    for (int r = 0; r < 4; ++r) { mrun[r] = -1e30f; lrun[r] = 0.f; }
    const f16* phib = phi + (size_t)b * MM * CI;
    const f16* gb = gx + (size_t)b * CI * MM;
    f16* Pw = Pl + wv * 16 * 64;
    for (int m0 = 0; m0 < MM; m0 += 64) {
        int S = (MM - m0) < 64 ? (MM - m0) : 64;   // 64 or 32
        // stage phi chunk: S rows x 16 slots
        for (int s = threadIdx.x; s < S * 16; s += 256) {
            int row = s >> 4, sl = s & 15;
            f16x8 v = *(const f16x8*)(phib + (size_t)(m0 + row) * CI + sl * 8);
            *(f16x8*)(Bp + row * 128 + ((sl * 8) ^ ((row & 7) << 3))) = v;
        }
        // stage g chunk: 128 rows x up to 8 slots (guard for partial chunk)
        for (int s = threadIdx.x; s < 128 * 8; s += 256) {
            int row = s >> 3, sl = s & 7;
            if (m0 + sl * 8 < MM) {
                f16x8 v = *(const f16x8*)(gb + (size_t)row * MM + m0 + sl * 8);
                *(f16x8*)(Bg + row * 64 + ((sl * 8) ^ ((row & 7) << 3))) = v;
            }
        }
        __syncthreads();
        int NF = S >> 4;  // 4 or 2
        // f = theta @ phi^T  (C: col=m_local, row=n_local)
        f32x4 ff[4];
        for (int mf = 0; mf < NF; ++mf) {
            for (int r = 0; r < 4; ++r) ff[mf][r] = 0.f;
            int rm = mf * 16 + (ln & 15);
            for (int kc = 0; kc < 4; ++kc) {
                f16x8 bf = *(const f16x8*)(Bp + rm * 128 + ((kc * 32 + (ln >> 4) * 8) ^ ((rm & 7) << 3)));
                ff[mf] = mfma16(af[kc], bf, ff[mf]);
            }
        }
        // online softmax over this chunk
        float ps[4];
        for (int r = 0; r < 4; ++r) {
            float mx = ff[0][r];
            for (int mf = 1; mf < NF; ++mf) mx = fmaxf(mx, ff[mf][r]);
            mx = fmaxf(mx, __shfl_xor(mx, 1));
            mx = fmaxf(mx, __shfl_xor(mx, 2));
            mx = fmaxf(mx, __shfl_xor(mx, 4));
            mx = fmaxf(mx, __shfl_xor(mx, 8));
            float mnew = fmaxf(mrun[r], mx);
            float scl = __expf(mrun[r] - mnew);
            lrun[r] *= scl;
            mrun[r] = mnew;
            for (int cif = 0; cif < 8; ++cif) yac[cif][r] *= scl;
            ps[r] = 0.f;
        }
        for (int mf = 0; mf < NF; ++mf) {
            int cm = mf * 16 + (ln & 15);
            for (int r = 0; r < 4; ++r) {
                float p = __expf(ff[mf][r] - mrun[r]);
                ps[r] += p;
                int rr = (ln >> 4) * 4 + r;
                Pw[rr * 64 + (cm ^ ((rr & 7) << 3))] = (f16)p;
            }
        }
        for (int r = 0; r < 4; ++r) {
            float s = ps[r];
            s += __shfl_xor(s, 1); s += __shfl_xor(s, 2);
            s += __shfl_xor(s, 4); s += __shfl_xor(s, 8);
            lrun[r] += s;
        }
        // PV: y += P @ g
        for (int kc2 = 0; kc2 < (S >> 5); ++kc2) {
            int row = ln & 15;
            f16x8 pa = *(const f16x8*)(Pw + row * 64 + ((kc2 * 32 + (ln >> 4) * 8) ^ ((row & 7) << 3)));
            for (int cif = 0; cif < 8; ++cif) {
                int rc = cif * 16 + (ln & 15);
                f16x8 bg = *(const f16x8*)(Bg + rc * 64 + ((kc2 * 32 + (ln >> 4) * 8) ^ ((rc & 7) << 3)));
                yac[cif] = mfma16(pa, bg, yac[cif]);
            }
        }
        __syncthreads();
    }
    f16* yb = y + (size_t)b * NN * CI;
    for (int cif = 0; cif < 8; ++cif)
        for (int r = 0; r < 4; ++r) {
            int n = n0 + wv * 16 + (ln >> 4) * 4 + r;
            int ci = cif * 16 + (ln & 15);
            yb[(size_t)n * CI + ci] = (f16)(yac[cif][r] / lrun[r]);
        }
}

// ---------------- K4: out = BN(wW @ y^T) + x ----------------
__global__ __launch_bounds__(256) void k_out(const f16* __restrict__ wWh, const f16* __restrict__ y,
                                             const float* __restrict__ x, const float* __restrict__ sc,
                                             const float* __restrict__ ofb, float* __restrict__ out) {
    int bid = blockIdx.x;                 // BB*196*2
    int b = bid / (196 * 2); int rem = bid % (196 * 2);
    int nt = rem >> 1, ct = rem & 1;
    int n0 = nt * 64, co0 = ct * 128;
    __shared__ f16 Ws[128 * 128];         // [co][ci] swizzled
    __shared__ f16 Ys[64 * 128];          // [n][ci] swizzled
    for (int s = threadIdx.x; s < 128 * 16; s += 256) {
        int row = s >> 4, sl = s & 15;
        f16x8 v = *(const f16x8*)(wWh + (size_t)(co0 + row) * CI + sl * 8);
        *(f16x8*)(Ws + row * 128 + ((sl * 8) ^ ((row & 7) << 3))) = v;
    }
    const f16* yb = y + (size_t)b * NN * CI + (size_t)n0 * CI;
    for (int s = threadIdx.x; s < 64 * 16; s += 256) {
        int row = s >> 4, sl = s & 15;
        f16x8 v = *(const f16x8*)(yb + (size_t)row * CI + sl * 8);
        *(f16x8*)(Ys + row * 128 + ((sl * 8) ^ ((row & 7) << 3))) = v;
    }
    __syncthreads();
    int wv = threadIdx.x >> 6, ln = threadIdx.x & 63;
    int wc = (wv >> 1) * 64, wn = (wv & 1) * 32;
    f32x4 acc[4][2];
    for (int i = 0; i < 4; ++i) for (int j = 0; j < 2; ++j)
        for (int r = 0; r < 4; ++r) acc[i][j][r] = 0.f;
    for (int kc = 0; kc < 4; ++kc) {
        int klo = kc * 32 + (ln >> 4) * 8;
        f16x8 afr[4], bfr[2];
        for (int i = 0; i < 4; ++i) {
            int rc = wc + i * 16 + (ln & 15);
            afr[i] = *(const f16x8*)(Ws + rc * 128 + (klo ^ ((rc & 7) << 3)));
        }
        for (int j = 0; j < 2; ++j) {
            int rn = wn + j * 16 + (ln & 15);
            bfr[j] = *(const f16x8*)(Ys + rn * 128 + (klo ^ ((rn & 7) << 3)));
        }
        for (int i = 0; i < 4; ++i)
            for (int j = 0; j < 2; ++j)
                acc[i][j] = mfma16(afr[i], bfr[j], acc[i][j]);
    }
    const float* xb = x + (size_t)b * CC * NN;
    float* ob = out + (size_t)b * CC * NN;
    for (int i = 0; i < 4; ++i)
        for (int j = 0; j < 2; ++j)
            for (int r = 0; r < 4; ++r) {
                int co = co0 + wc + i * 16 + (ln >> 4) * 4 + r;
                int n = n0 + wn + j * 16 + (ln & 15);
                size_t idx = (size_t)co * NN + n;
                ob[idx] = acc[i][j][r] * sc[co] + ofb[co] + xb[idx];
            }
}

extern "C" void kernel_launch(void* const* d_in, const int* in_sizes, int n_in,
                              void* d_out, int out_size, void* d_ws, size_t ws_size,
                              hipStream_t stream) {
    const float* x    = (const float*)d_in[0];
    const float* wg   = (const float*)d_in[1];
    const float* bg   = (const float*)d_in[2];
    const float* wth  = (const float*)d_in[3];
    const float* bth  = (const float*)d_in[4];
    const float* wph  = (const float*)d_in[5];
    const float* bph  = (const float*)d_in[6];
    const float* wW   = (const float*)d_in[7];
    const float* bW   = (const float*)d_in[8];
    const float* gam  = (const float*)d_in[9];
    const float* bet  = (const float*)d_in[10];
    const float* mean = (const float*)d_in[11];
    const float* var  = (const float*)d_in[12];
    if (ws_size < (size_t)WS_NEED) return;
    char* ws = (char*)d_ws;
    f16* w3t = (f16*)(ws + OFF_W3T);
    f16* wWh = (f16*)(ws + OFF_WWH);
    f16* b3  = (f16*)(ws + OFF_B3);
    float* sc  = (float*)(ws + OFF_SC);
    float* ofb = (float*)(ws + OFF_OFB);
    f16* xT  = (f16*)(ws + OFF_XT);
    f16* tpg = (f16*)(ws + OFF_TPG);
    f16* phi = (f16*)(ws + OFF_PHI);
    f16* gx  = (f16*)(ws + OFF_G);
    f16* yy  = (f16*)(ws + OFF_Y);
    float* out = (float*)d_out;

    k_prep<<<dim3(384), dim3(256), 0, stream>>>(wg, bg, wth, bth, wph, bph, wW, bW,
                                                gam, bet, mean, var, w3t, wWh, b3, sc, ofb);
    k_xt  <<<dim3(BB * 196 * 4), dim3(256), 0, stream>>>(x, xT);
    k_conv<<<dim3(BB * 98 * 3), dim3(256), 0, stream>>>(xT, w3t, b3, tpg);
    k_pool<<<dim3(BB * TP * HP), dim3(256), 0, stream>>>(tpg, phi, gx);
    k_attn<<<dim3(BB * 196), dim3(256), 0, stream>>>(tpg, phi, gx, yy);
    k_out <<<dim3(BB * 196 * 2), dim3(256), 0, stream>>>(wWh, yy, x, sc, ofb, out);
}

// Round 2
// 313.074 us; speedup vs baseline: 1.1701x; 1.1701x over previous
//
#include <hip/hip_runtime.h>
#include <math.h>

typedef _Float16 f16;
typedef _Float16 f16x8 __attribute__((ext_vector_type(8)));
typedef float f32x4 __attribute__((ext_vector_type(4)));

#define BB 4
#define CC 256
#define CI 128
#define NN 12544
#define MM 1568
#define TP 8
#define HP 14
#define WP 14

// workspace byte offsets (all 16B aligned)
#define OFF_W3T 0u
#define OFF_WWH 196608u
#define OFF_B3  262144u
#define OFF_SC  263168u
#define OFF_OFB 264192u
#define OFF_XT  265216u
#define OFF_TPG (OFF_XT + 25690112u)
#define OFF_PHI (OFF_TPG + 38535168u)
#define OFF_G   (OFF_PHI + 1605632u)
#define OFF_Y   (OFF_G + 1605632u)
#define WS_NEED (OFF_Y + 12845056u)

static __device__ __forceinline__ f32x4 mfma16(f16x8 a, f16x8 b, f32x4 c) {
    return __builtin_amdgcn_mfma_f32_16x16x32_f16(a, b, c, 0, 0, 0);
}

// ---------------- K0a: weight prep ----------------
__global__ __launch_bounds__(256) void k_prep(
    const float* __restrict__ wg, const float* __restrict__ bg,
    const float* __restrict__ wth, const float* __restrict__ bth,
    const float* __restrict__ wph, const float* __restrict__ bph,
    const float* __restrict__ wW, const float* __restrict__ bW,
    const float* __restrict__ gam, const float* __restrict__ bet,
    const float* __restrict__ mean, const float* __restrict__ var,
    f16* __restrict__ w3t, f16* __restrict__ wWh, f16* __restrict__ b3,
    float* __restrict__ sc, float* __restrict__ ofb) {
    int r = blockIdx.x;          // 0..383
    int c = threadIdx.x;         // 0..255
    const float* src = (r < 128) ? (wth + (size_t)r * CC)
                     : (r < 256) ? (wph + (size_t)(r - 128) * CC)
                                 : (wg + (size_t)(r - 256) * CC);
    w3t[(size_t)r * CC + c] = (f16)src[c];
    if (c == 0) {
        float bv = (r < 128) ? bth[r] : (r < 256) ? bph[r - 128] : bg[r - 256];
        b3[r] = (f16)bv;
    }
    if (r < 256) {
        if (c < 128) wWh[(size_t)r * CI + c] = (f16)wW[(size_t)r * CI + c];
        if (c == 0) {
            float s = gam[r] * rsqrtf(var[r] + 1e-5f);
            sc[r] = s;
            ofb[r] = (bW[r] - mean[r]) * s + bet[r];
        }
    }
}

// ---------------- K0b: x (c,n) f32 -> xT (n,c) fp16 ----------------
__global__ __launch_bounds__(256) void k_xt(const float* __restrict__ x, f16* __restrict__ xT) {
    int bid = blockIdx.x;                 // BB*196*4
    int b = bid / (196 * 4); int rem = bid % (196 * 4);
    int nt = rem / 4, ct = rem % 4;
    int n0 = nt * 64, c0 = ct * 64;
    __shared__ float tile[64][65];
    const float* xb = x + (size_t)b * CC * NN;
    for (int p = 0; p < 16; ++p) {
        int idx = p * 256 + threadIdx.x;
        int i = idx >> 6, j = idx & 63;   // i=c-local, j=n-local
        tile[i][j] = xb[(size_t)(c0 + i) * NN + n0 + j];
    }
    __syncthreads();
    f16* xTb = xT + (size_t)b * NN * CC;
    for (int p = 0; p < 16; ++p) {
        int idx = p * 256 + threadIdx.x;
        int n = idx >> 6, c = idx & 63;
        xTb[(size_t)(n0 + n) * CC + c0 + c] = (f16)tile[c][n];
    }
}

// ---------------- K1: fused conv GEMM  tpg[n][0:384] = xT(n,:) @ w3t^T + b3 ----------------
__global__ __launch_bounds__(256) void k_conv(const f16* __restrict__ xT, const f16* __restrict__ w3t,
                                              const f16* __restrict__ b3, f16* __restrict__ tpg) {
    int bid = blockIdx.x;                 // BB*98*3
    int b = bid / (98 * 3); int rem = bid % (98 * 3);
    int nt = rem / 3, ct = rem % 3;
    int n0 = nt * 128, co0 = ct * 128;
    __shared__ f16 As[128 * 64];          // [n][k] swizzled, 64-half rows
    __shared__ f16 Bs[128 * 64];          // [co][k] swizzled
    const f16* xb = xT + (size_t)b * NN * CC + (size_t)n0 * CC;
    const f16* wb = w3t + (size_t)co0 * CC;
    int wv = threadIdx.x >> 6, ln = threadIdx.x & 63;
    int wr = (wv & 1) * 64, wc = (wv >> 1) * 64;
    f32x4 acc[4][4];
    for (int i = 0; i < 4; ++i) for (int j = 0; j < 4; ++j)
        for (int r = 0; r < 4; ++r) acc[i][j][r] = 0.f;
    for (int ks = 0; ks < 4; ++ks) {
        for (int s = threadIdx.x; s < 1024; s += 256) {
            int row = s >> 3, sl = s & 7;
            f16x8 va = *(const f16x8*)(xb + (size_t)row * CC + ks * 64 + sl * 8);
            *(f16x8*)(As + row * 64 + ((sl * 8) ^ ((row & 7) << 3))) = va;
            f16x8 vb = *(const f16x8*)(wb + (size_t)row * CC + ks * 64 + sl * 8);
            *(f16x8*)(Bs + row * 64 + ((sl * 8) ^ ((row & 7) << 3))) = vb;
        }
        __syncthreads();
        for (int kc = 0; kc < 2; ++kc) {
            int klo = kc * 32 + ((ln >> 4) * 8);
            f16x8 af[4], bf[4];
            for (int i = 0; i < 4; ++i) {
                int rn = wr + i * 16 + (ln & 15);
                af[i] = *(const f16x8*)(As + rn * 64 + (klo ^ ((rn & 7) << 3)));
                int rc = wc + i * 16 + (ln & 15);
                bf[i] = *(const f16x8*)(Bs + rc * 64 + (klo ^ ((rc & 7) << 3)));
            }
            for (int i = 0; i < 4; ++i)
                for (int j = 0; j < 4; ++j)
                    acc[i][j] = mfma16(af[i], bf[j], acc[i][j]);
        }
        __syncthreads();
    }
    f16* ob = tpg + (size_t)b * NN * 384 + (size_t)n0 * 384 + co0;
    for (int j = 0; j < 4; ++j) {
        float bias = (float)b3[co0 + wc + j * 16 + (ln & 15)];
        for (int i = 0; i < 4; ++i)
            for (int r = 0; r < 4; ++r) {
                int n = wr + i * 16 + (ln >> 4) * 4 + r;
                int co = wc + j * 16 + (ln & 15);
                ob[(size_t)n * 384 + co] = (f16)(acc[i][j][r] + bias);
            }
    }
}

// ---------------- K2: maxpool -> phi (m,ci), g (ci,m) ----------------
__global__ __launch_bounds__(256) void k_pool(const f16* __restrict__ tpg,
                                              f16* __restrict__ phi, f16* __restrict__ gx) {
    int bid = blockIdx.x;                 // BB*TP*HP
    int b = bid / (TP * HP); int rem = bid % (TP * HP);
    int tp = rem / HP, hp = rem % HP;
    const f16* base = tpg + (size_t)b * NN * 384;
    for (int idx = threadIdx.x; idx < WP * 128; idx += 256) {
        int wp = idx >> 7, ci = idx & 127;
        f16 mp = (f16)(-60000.0f), mg = (f16)(-60000.0f);
        for (int dt = 0; dt < 2; ++dt)
            for (int dh = 0; dh < 2; ++dh)
                for (int dw = 0; dw < 2; ++dw) {
                    int n = (2 * tp + dt) * 784 + (2 * hp + dh) * 28 + (2 * wp + dw);
                    f16 vp = base[(size_t)n * 384 + 128 + ci];
                    f16 vg = base[(size_t)n * 384 + 256 + ci];
                    mp = vp > mp ? vp : mp;
                    mg = vg > mg ? vg : mg;
                }
        int m = tp * 196 + hp * 14 + wp;
        phi[(size_t)b * MM * CI + (size_t)m * CI + ci] = mp;
        gx[(size_t)b * CI * MM + (size_t)ci * MM + m] = mg;
    }
}

// ---------------- K3: flash attention  y(n,ci) = softmax(theta@phi) @ g ----------------
// Chunk compute: all loop bounds COMPILE-TIME (NF = #16-key frags). Runtime bounds
// previously put ff[] in scratch (rule #20) -> 5x slowdown.
template<int NF>
__device__ __forceinline__ void attn_chunk(const f16* __restrict__ Bp, const f16* __restrict__ Bg,
                                           f16* __restrict__ Pw, const f16x8* af,
                                           f32x4* yac, float* mrun, float* lrun, int ln) {
    f32x4 ff[NF];
    // QK^T: f = theta @ phi^T
    __builtin_amdgcn_s_setprio(1);
    #pragma unroll
    for (int mf = 0; mf < NF; ++mf) {
        #pragma unroll
        for (int r = 0; r < 4; ++r) ff[mf][r] = 0.f;
        int rm = mf * 16 + (ln & 15);
        #pragma unroll
        for (int kc = 0; kc < 4; ++kc) {
            f16x8 bf = *(const f16x8*)(Bp + rm * 128 + ((kc * 32 + (ln >> 4) * 8) ^ ((rm & 7) << 3)));
            ff[mf] = mfma16(af[kc], bf, ff[mf]);
        }
    }
    __builtin_amdgcn_s_setprio(0);
    // online softmax with defer-max (THR=8): p bounded by e^8=2981, fits f16
    #pragma unroll
    for (int r = 0; r < 4; ++r) {
        float mx = ff[0][r];
        #pragma unroll
        for (int mf = 1; mf < NF; ++mf) mx = fmaxf(mx, ff[mf][r]);
        mx = fmaxf(mx, __shfl_xor(mx, 1));
        mx = fmaxf(mx, __shfl_xor(mx, 2));
        mx = fmaxf(mx, __shfl_xor(mx, 4));
        mx = fmaxf(mx, __shfl_xor(mx, 8));
        if (mx > mrun[r] + 8.f) {
            float scl = __expf(mrun[r] - mx);
            lrun[r] *= scl;
            #pragma unroll
            for (int cif = 0; cif < 8; ++cif) yac[cif][r] *= scl;
            mrun[r] = mx;
        }
    }
    float ps[4];
    #pragma unroll
    for (int r = 0; r < 4; ++r) ps[r] = 0.f;
    #pragma unroll
    for (int mf = 0; mf < NF; ++mf) {
        int cm = mf * 16 + (ln & 15);
        #pragma unroll
        for (int r = 0; r < 4; ++r) {
            float p = __expf(ff[mf][r] - mrun[r]);
            ps[r] += p;
            int rr = (ln >> 4) * 4 + r;
            Pw[rr * 64 + (cm ^ ((rr & 7) << 3))] = (f16)p;
        }
    }
    #pragma unroll
    for (int r = 0; r < 4; ++r) {
        float s = ps[r];
        s += __shfl_xor(s, 1); s += __shfl_xor(s, 2);
        s += __shfl_xor(s, 4); s += __shfl_xor(s, 8);
        lrun[r] += s;
    }
    // PV: y += P @ g
    #pragma unroll
    for (int kc2 = 0; kc2 < NF / 2; ++kc2) {
        int row = ln & 15;
        f16x8 pa = *(const f16x8*)(Pw + row * 64 + ((kc2 * 32 + (ln >> 4) * 8) ^ ((row & 7) << 3)));
        __builtin_amdgcn_s_setprio(1);
        #pragma unroll
        for (int cif = 0; cif < 8; ++cif) {
            int rc = cif * 16 + (ln & 15);
            f16x8 bg = *(const f16x8*)(Bg + rc * 64 + ((kc2 * 32 + (ln >> 4) * 8) ^ ((rc & 7) << 3)));
            yac[cif] = mfma16(pa, bg, yac[cif]);
        }
        __builtin_amdgcn_s_setprio(0);
    }
}

// issue-early staging (T14): global -> regs (issued before compute), regs -> LDS after barrier
template<int S>
__device__ __forceinline__ void stage_load(const f16* __restrict__ phib, const f16* __restrict__ gb,
                                           int m0, int tid, f16x8* sp, f16x8* sg) {
    #pragma unroll
    for (int p = 0; p < S / 16; ++p) {
        int s = p * 256 + tid;
        int row = s >> 4, sl = s & 15;
        sp[p] = *(const f16x8*)(phib + (size_t)(m0 + row) * CI + sl * 8);
    }
    #pragma unroll
    for (int p = 0; p < S / 16; ++p) {
        int s = p * 256 + tid;
        int row = (S == 64) ? (s >> 3) : (s >> 2);
        int sl  = (S == 64) ? (s & 7) : (s & 3);
        sg[p] = *(const f16x8*)(gb + (size_t)row * MM + m0 + sl * 8);
    }
}

template<int S>
__device__ __forceinline__ void stage_write(f16* __restrict__ Bp, f16* __restrict__ Bg,
                                            int tid, const f16x8* sp, const f16x8* sg) {
    #pragma unroll
    for (int p = 0; p < S / 16; ++p) {
        int s = p * 256 + tid;
        int row = s >> 4, sl = s & 15;
        *(f16x8*)(Bp + row * 128 + ((sl * 8) ^ ((row & 7) << 3))) = sp[p];
    }
    #pragma unroll
    for (int p = 0; p < S / 16; ++p) {
        int s = p * 256 + tid;
        int row = (S == 64) ? (s >> 3) : (s >> 2);
        int sl  = (S == 64) ? (s & 7) : (s & 3);
        *(f16x8*)(Bg + row * 64 + ((sl * 8) ^ ((row & 7) << 3))) = sg[p];
    }
}

__global__ __launch_bounds__(256) void k_attn(const f16* __restrict__ tpg, const f16* __restrict__ phi,
                                              const f16* __restrict__ gx, f16* __restrict__ y) {
    int bid = blockIdx.x;                 // BB*196
    int b = bid / 196; int nt = bid % 196;
    int n0 = nt * 64;
    __shared__ f16 Bp[64 * 128];          // phi chunk [m][ci], swizzled
    __shared__ f16 Bg[128 * 64];          // g chunk [ci][m], swizzled
    __shared__ f16 Pl[4 * 16 * 64];       // per-wave P [16][64] swizzled
    int tid = threadIdx.x;
    int wv = tid >> 6, ln = tid & 63;
    // theta A-fragments (kept in regs for whole kernel)
    f16x8 af[4];
    {
        int n = n0 + wv * 16 + (ln & 15);
        const f16* rowp = tpg + (size_t)b * NN * 384 + (size_t)n * 384;
        #pragma unroll
        for (int kc = 0; kc < 4; ++kc)
            af[kc] = *(const f16x8*)(rowp + kc * 32 + (ln >> 4) * 8);
    }
    f32x4 yac[8];
    #pragma unroll
    for (int i = 0; i < 8; ++i)
        #pragma unroll
        for (int r = 0; r < 4; ++r) yac[i][r] = 0.f;
    float mrun[4], lrun[4];
    #pragma unroll
    for (int r = 0; r < 4; ++r) { mrun[r] = -1e30f; lrun[r] = 0.f; }
    const f16* phib = phi + (size_t)b * MM * CI;
    const f16* gb = gx + (size_t)b * CI * MM;
    f16* Pw = Pl + wv * 16 * 64;

    f16x8 sp[4], sg[4];
    // prologue: stage chunk 0
    stage_load<64>(phib, gb, 0, tid, sp, sg);
    stage_write<64>(Bp, Bg, tid, sp, sg);
    __syncthreads();
    // main: 23 full chunks with prefetch of next
    for (int t = 0; t < 23; ++t) {
        stage_load<64>(phib, gb, (t + 1) * 64, tid, sp, sg);
        attn_chunk<4>(Bp, Bg, Pw, af, yac, mrun, lrun, ln);
        __syncthreads();
        stage_write<64>(Bp, Bg, tid, sp, sg);
        __syncthreads();
    }
    // chunk 23 with tail prefetch (tail = 32 keys at m0=1536)
    stage_load<32>(phib, gb, 1536, tid, sp, sg);
    attn_chunk<4>(Bp, Bg, Pw, af, yac, mrun, lrun, ln);
    __syncthreads();
    stage_write<32>(Bp, Bg, tid, sp, sg);
    __syncthreads();
    attn_chunk<2>(Bp, Bg, Pw, af, yac, mrun, lrun, ln);

    f16* yb = y + (size_t)b * NN * CI;
    #pragma unroll
    for (int cif = 0; cif < 8; ++cif)
        #pragma unroll
        for (int r = 0; r < 4; ++r) {
            int n = n0 + wv * 16 + (ln >> 4) * 4 + r;
            int ci = cif * 16 + (ln & 15);
            yb[(size_t)n * CI + ci] = (f16)(yac[cif][r] / lrun[r]);
        }
}

// ---------------- K4: out = BN(wW @ y^T) + x ----------------
__global__ __launch_bounds__(256) void k_out(const f16* __restrict__ wWh, const f16* __restrict__ y,
                                             const float* __restrict__ x, const float* __restrict__ sc,
                                             const float* __restrict__ ofb, float* __restrict__ out) {
    int bid = blockIdx.x;                 // BB*196*2
    int b = bid / (196 * 2); int rem = bid % (196 * 2);
    int nt = rem >> 1, ct = rem & 1;
    int n0 = nt * 64, co0 = ct * 128;
    __shared__ f16 Ws[128 * 128];         // [co][ci] swizzled
    __shared__ f16 Ys[64 * 128];          // [n][ci] swizzled
    for (int s = threadIdx.x; s < 128 * 16; s += 256) {
        int row = s >> 4, sl = s & 15;
        f16x8 v = *(const f16x8*)(wWh + (size_t)(co0 + row) * CI + sl * 8);
        *(f16x8*)(Ws + row * 128 + ((sl * 8) ^ ((row & 7) << 3))) = v;
    }
    const f16* yb = y + (size_t)b * NN * CI + (size_t)n0 * CI;
    for (int s = threadIdx.x; s < 64 * 16; s += 256) {
        int row = s >> 4, sl = s & 15;
        f16x8 v = *(const f16x8*)(yb + (size_t)row * CI + sl * 8);
        *(f16x8*)(Ys + row * 128 + ((sl * 8) ^ ((row & 7) << 3))) = v;
    }
    __syncthreads();
    int wv = threadIdx.x >> 6, ln = threadIdx.x & 63;
    int wc = (wv >> 1) * 64, wn = (wv & 1) * 32;
    f32x4 acc[4][2];
    for (int i = 0; i < 4; ++i) for (int j = 0; j < 2; ++j)
        for (int r = 0; r < 4; ++r) acc[i][j][r] = 0.f;
    for (int kc = 0; kc < 4; ++kc) {
        int klo = kc * 32 + (ln >> 4) * 8;
        f16x8 afr[4], bfr[2];
        for (int i = 0; i < 4; ++i) {
            int rc = wc + i * 16 + (ln & 15);
            afr[i] = *(const f16x8*)(Ws + rc * 128 + (klo ^ ((rc & 7) << 3)));
        }
        for (int j = 0; j < 2; ++j) {
            int rn = wn + j * 16 + (ln & 15);
            bfr[j] = *(const f16x8*)(Ys + rn * 128 + (klo ^ ((rn & 7) << 3)));
        }
        for (int i = 0; i < 4; ++i)
            for (int j = 0; j < 2; ++j)
                acc[i][j] = mfma16(afr[i], bfr[j], acc[i][j]);
    }
    const float* xb = x + (size_t)b * CC * NN;
    float* ob = out + (size_t)b * CC * NN;
    for (int i = 0; i < 4; ++i)
        for (int j = 0; j < 2; ++j)
            for (int r = 0; r < 4; ++r) {
                int co = co0 + wc + i * 16 + (ln >> 4) * 4 + r;
                int n = n0 + wn + j * 16 + (ln & 15);
                size_t idx = (size_t)co * NN + n;
                ob[idx] = acc[i][j][r] * sc[co] + ofb[co] + xb[idx];
            }
}

extern "C" void kernel_launch(void* const* d_in, const int* in_sizes, int n_in,
                              void* d_out, int out_size, void* d_ws, size_t ws_size,
                              hipStream_t stream) {
    const float* x    = (const float*)d_in[0];
    const float* wg   = (const float*)d_in[1];
    const float* bg   = (const float*)d_in[2];
    const float* wth  = (const float*)d_in[3];
    const float* bth  = (const float*)d_in[4];
    const float* wph  = (const float*)d_in[5];
    const float* bph  = (const float*)d_in[6];
    const float* wW   = (const float*)d_in[7];
    const float* bW   = (const float*)d_in[8];
    const float* gam  = (const float*)d_in[9];
    const float* bet  = (const float*)d_in[10];
    const float* mean = (const float*)d_in[11];
    const float* var  = (const float*)d_in[12];
    if (ws_size < (size_t)WS_NEED) return;
    char* ws = (char*)d_ws;
    f16* w3t = (f16*)(ws + OFF_W3T);
    f16* wWh = (f16*)(ws + OFF_WWH);
    f16* b3  = (f16*)(ws + OFF_B3);
    float* sc  = (float*)(ws + OFF_SC);
    float* ofb = (float*)(ws + OFF_OFB);
    f16* xT  = (f16*)(ws + OFF_XT);
    f16* tpg = (f16*)(ws + OFF_TPG);
    f16* phi = (f16*)(ws + OFF_PHI);
    f16* gx  = (f16*)(ws + OFF_G);
    f16* yy  = (f16*)(ws + OFF_Y);
    float* out = (float*)d_out;

    k_prep<<<dim3(384), dim3(256), 0, stream>>>(wg, bg, wth, bth, wph, bph, wW, bW,
                                                gam, bet, mean, var, w3t, wWh, b3, sc, ofb);
    k_xt  <<<dim3(BB * 196 * 4), dim3(256), 0, stream>>>(x, xT);
    k_conv<<<dim3(BB * 98 * 3), dim3(256), 0, stream>>>(xT, w3t, b3, tpg);
    k_pool<<<dim3(BB * TP * HP), dim3(256), 0, stream>>>(tpg, phi, gx);
    k_attn<<<dim3(BB * 196), dim3(256), 0, stream>>>(tpg, phi, gx, yy);
    k_out <<<dim3(BB * 196 * 2), dim3(256), 0, stream>>>(wWh, yy, x, sc, ofb, out);
}

// Round 3
// 146.424 us; speedup vs baseline: 2.5018x; 2.1381x over previous
//
#include <hip/hip_runtime.h>
#include <math.h>

typedef _Float16 f16;
typedef _Float16 f16x8 __attribute__((ext_vector_type(8)));
typedef float f32x4 __attribute__((ext_vector_type(4)));
typedef float f32x16 __attribute__((ext_vector_type(16)));

#define BB 4
#define CC 256
#define CI 128
#define NN 12544
#define MM 1568
#define TP 8
#define HP 14
#define WP 14

// workspace byte offsets (all 16B aligned)
#define OFF_W3T 0u
#define OFF_WWH 196608u
#define OFF_B3  262144u
#define OFF_SC  263168u
#define OFF_OFB 264192u
#define OFF_XT  265216u
#define OFF_TPG (OFF_XT + 25690112u)
#define OFF_PHI (OFF_TPG + 38535168u)
#define OFF_G   (OFF_PHI + 1605632u)
#define OFF_Y   (OFF_G + 1605632u)
#define WS_NEED (OFF_Y + 12845056u)

static __device__ __forceinline__ f32x4 mfma16(f16x8 a, f16x8 b, f32x4 c) {
    return __builtin_amdgcn_mfma_f32_16x16x32_f16(a, b, c, 0, 0, 0);
}
static __device__ __forceinline__ f32x16 mfma32(f16x8 a, f16x8 b, f32x16 c) {
    return __builtin_amdgcn_mfma_f32_32x32x16_f16(a, b, c, 0, 0, 0);
}
static __device__ __forceinline__ unsigned pkrtz(float a, float b) {
    auto h = __builtin_amdgcn_cvt_pkrtz(a, b);
    return __builtin_bit_cast(unsigned, h);
}

// ---------------- K0a: weight prep ----------------
__global__ __launch_bounds__(256) void k_prep(
    const float* __restrict__ wg, const float* __restrict__ bg,
    const float* __restrict__ wth, const float* __restrict__ bth_,
    const float* __restrict__ wph, const float* __restrict__ bph,
    const float* __restrict__ wW, const float* __restrict__ bW,
    const float* __restrict__ gam, const float* __restrict__ bet,
    const float* __restrict__ mean, const float* __restrict__ var,
    f16* __restrict__ w3t, f16* __restrict__ wWh, f16* __restrict__ b3,
    float* __restrict__ sc, float* __restrict__ ofb) {
    int r = blockIdx.x;          // 0..383
    int c = threadIdx.x;         // 0..255
    const float* src = (r < 128) ? (wth + (size_t)r * CC)
                     : (r < 256) ? (wph + (size_t)(r - 128) * CC)
                                 : (wg + (size_t)(r - 256) * CC);
    w3t[(size_t)r * CC + c] = (f16)src[c];
    if (c == 0) {
        float bv = (r < 128) ? bth_[r] : (r < 256) ? bph[r - 128] : bg[r - 256];
        b3[r] = (f16)bv;
    }
    if (r < 256) {
        if (c < 128) wWh[(size_t)r * CI + c] = (f16)wW[(size_t)r * CI + c];
        if (c == 0) {
            float s = gam[r] * rsqrtf(var[r] + 1e-5f);
            sc[r] = s;
            ofb[r] = (bW[r] - mean[r]) * s + bet[r];
        }
    }
}

// ---------------- K0b: x (c,n) f32 -> xT (n,c) fp16 ----------------
__global__ __launch_bounds__(256) void k_xt(const float* __restrict__ x, f16* __restrict__ xT) {
    int bid = blockIdx.x;                 // BB*196*4
    int b = bid / (196 * 4); int rem = bid % (196 * 4);
    int nt = rem / 4, ct = rem % 4;
    int n0 = nt * 64, c0 = ct * 64;
    __shared__ float tile[64][65];
    const float* xb = x + (size_t)b * CC * NN;
    for (int p = 0; p < 16; ++p) {
        int idx = p * 256 + threadIdx.x;
        int i = idx >> 6, j = idx & 63;   // i=c-local, j=n-local
        tile[i][j] = xb[(size_t)(c0 + i) * NN + n0 + j];
    }
    __syncthreads();
    f16* xTb = xT + (size_t)b * NN * CC;
    for (int p = 0; p < 16; ++p) {
        int idx = p * 256 + threadIdx.x;
        int n = idx >> 6, c = idx & 63;
        xTb[(size_t)(n0 + n) * CC + c0 + c] = (f16)tile[c][n];
    }
}

// ---------------- K1: fused conv GEMM  tpg[n][0:384] = xT(n,:) @ w3t^T + b3 ----------------
__global__ __launch_bounds__(256) void k_conv(const f16* __restrict__ xT, const f16* __restrict__ w3t,
                                              const f16* __restrict__ b3, f16* __restrict__ tpg) {
    int bid = blockIdx.x;                 // BB*98*3
    int b = bid / (98 * 3); int rem = bid % (98 * 3);
    int nt = rem / 3, ct = rem % 3;
    int n0 = nt * 128, co0 = ct * 128;
    __shared__ f16 As[128 * 64];          // [n][k] swizzled, 64-half rows
    __shared__ f16 Bs[128 * 64];          // [co][k] swizzled
    const f16* xb = xT + (size_t)b * NN * CC + (size_t)n0 * CC;
    const f16* wb = w3t + (size_t)co0 * CC;
    int wv = threadIdx.x >> 6, ln = threadIdx.x & 63;
    int wr = (wv & 1) * 64, wc = (wv >> 1) * 64;
    f32x4 acc[4][4];
    for (int i = 0; i < 4; ++i) for (int j = 0; j < 4; ++j)
        for (int r = 0; r < 4; ++r) acc[i][j][r] = 0.f;
    for (int ks = 0; ks < 4; ++ks) {
        for (int s = threadIdx.x; s < 1024; s += 256) {
            int row = s >> 3, sl = s & 7;
            f16x8 va = *(const f16x8*)(xb + (size_t)row * CC + ks * 64 + sl * 8);
            *(f16x8*)(As + row * 64 + ((sl * 8) ^ ((row & 7) << 3))) = va;
            f16x8 vb = *(const f16x8*)(wb + (size_t)row * CC + ks * 64 + sl * 8);
            *(f16x8*)(Bs + row * 64 + ((sl * 8) ^ ((row & 7) << 3))) = vb;
        }
        __syncthreads();
        for (int kc = 0; kc < 2; ++kc) {
            int klo = kc * 32 + ((ln >> 4) * 8);
            f16x8 af[4], bf[4];
            for (int i = 0; i < 4; ++i) {
                int rn = wr + i * 16 + (ln & 15);
                af[i] = *(const f16x8*)(As + rn * 64 + (klo ^ ((rn & 7) << 3)));
                int rc = wc + i * 16 + (ln & 15);
                bf[i] = *(const f16x8*)(Bs + rc * 64 + (klo ^ ((rc & 7) << 3)));
            }
            for (int i = 0; i < 4; ++i)
                for (int j = 0; j < 4; ++j)
                    acc[i][j] = mfma16(af[i], bf[j], acc[i][j]);
        }
        __syncthreads();
    }
    f16* ob = tpg + (size_t)b * NN * 384 + (size_t)n0 * 384 + co0;
    for (int j = 0; j < 4; ++j) {
        float bias = (float)b3[co0 + wc + j * 16 + (ln & 15)];
        for (int i = 0; i < 4; ++i)
            for (int r = 0; r < 4; ++r) {
                int n = wr + i * 16 + (ln >> 4) * 4 + r;
                int co = wc + j * 16 + (ln & 15);
                ob[(size_t)n * 384 + co] = (f16)(acc[i][j][r] + bias);
            }
    }
}

// ---------------- K2: maxpool -> phi (m,ci), g (ci,m) ----------------
__global__ __launch_bounds__(256) void k_pool(const f16* __restrict__ tpg,
                                              f16* __restrict__ phi, f16* __restrict__ gx) {
    int bid = blockIdx.x;                 // BB*TP*HP
    int b = bid / (TP * HP); int rem = bid % (TP * HP);
    int tp = rem / HP, hp = rem % HP;
    const f16* base = tpg + (size_t)b * NN * 384;
    for (int idx = threadIdx.x; idx < WP * 128; idx += 256) {
        int wp = idx >> 7, ci = idx & 127;
        f16 mp = (f16)(-60000.0f), mg = (f16)(-60000.0f);
        for (int dt = 0; dt < 2; ++dt)
            for (int dh = 0; dh < 2; ++dh)
                for (int dw = 0; dw < 2; ++dw) {
                    int n = (2 * tp + dt) * 784 + (2 * hp + dh) * 28 + (2 * wp + dw);
                    f16 vp = base[(size_t)n * 384 + 128 + ci];
                    f16 vg = base[(size_t)n * 384 + 256 + ci];
                    mp = vp > mp ? vp : mp;
                    mg = vg > mg ? vg : mg;
                }
        int m = tp * 196 + hp * 14 + wp;
        phi[(size_t)b * MM * CI + (size_t)m * CI + ci] = mp;
        gx[(size_t)b * CI * MM + (size_t)ci * MM + m] = mg;
    }
}

// ---------------- K3: swapped flash attention (32x32 MFMA) ----------------
// QK swapped: D[key][q] = phi_chunk . theta^T  -> lane owns one q column, keys in regs.
// PV swapped: D[ci][q]  = g^T . P              -> rescale/divide lane-local.
// Bp [64 keys][128 ci] elems XOR (row&15)<<3 ; Bg [128 ci][64 keys] elems XOR (row&7)<<3.

// issue-early staging (T14): global -> regs early; regs -> LDS after barrier
template<int S>
__device__ __forceinline__ void stage_load(const f16* __restrict__ phib, const f16* __restrict__ gb,
                                           int m0, int tid, f16x8* sp, f16x8* sg) {
    #pragma unroll
    for (int p = 0; p < S / 16; ++p) {
        int s = p * 256 + tid;
        int row = s >> 4, sl = s & 15;
        sp[p] = *(const f16x8*)(phib + (size_t)(m0 + row) * CI + sl * 8);
    }
    #pragma unroll
    for (int p = 0; p < S / 16; ++p) {
        int s = p * 256 + tid;
        int row = (S == 64) ? (s >> 3) : (s >> 2);
        int sl  = (S == 64) ? (s & 7) : (s & 3);
        sg[p] = *(const f16x8*)(gb + (size_t)row * MM + m0 + sl * 8);
    }
}

template<int S>
__device__ __forceinline__ void stage_write(f16* __restrict__ Bp, f16* __restrict__ Bg,
                                            int tid, const f16x8* sp, const f16x8* sg) {
    #pragma unroll
    for (int p = 0; p < S / 16; ++p) {
        int s = p * 256 + tid;
        int row = s >> 4, sl = s & 15;
        *(f16x8*)(Bp + row * 128 + ((sl * 8) ^ ((row & 15) << 3))) = sp[p];
    }
    #pragma unroll
    for (int p = 0; p < S / 16; ++p) {
        int s = p * 256 + tid;
        int row = (S == 64) ? (s >> 3) : (s >> 2);
        int sl  = (S == 64) ? (s & 7) : (s & 3);
        *(f16x8*)(Bg + row * 64 + ((sl * 8) ^ ((row & 7) << 3))) = sg[p];
    }
}

template<int KF>   // keyfrags of 32 keys; chunk = KF*32 keys
__device__ __forceinline__ void attn_chunk(const f16* __restrict__ Bp, const f16* __restrict__ Bg,
                                           const f16x8* bth, f32x16* yv,
                                           float& mrun, float& lrun, int lq, int hi) {
    f32x16 qk[KF];
    __builtin_amdgcn_s_setprio(1);
    #pragma unroll
    for (int kf = 0; kf < KF; ++kf) {
        #pragma unroll
        for (int r = 0; r < 16; ++r) qk[kf][r] = 0.f;
        int row = kf * 32 + lq;
        const f16* rp = Bp + row * 128;
        int sw = (row & 15) << 3;
        #pragma unroll
        for (int ks = 0; ks < 8; ++ks)
            qk[kf] = mfma32(*(const f16x8*)(rp + ((ks * 16 + hi * 8) ^ sw)), bth[ks], qk[kf]);
    }
    __builtin_amdgcn_s_setprio(0);
    // chunk max for this lane's q (own 16*KF values + partner half via shfl)
    float t[8];
    #pragma unroll
    for (int i = 0; i < 8; ++i) {
        t[i] = fmaxf(qk[0][i], qk[0][i + 8]);
        if (KF == 2) t[i] = fmaxf(t[i], fmaxf(qk[KF - 1][i], qk[KF - 1][i + 8]));
    }
    #pragma unroll
    for (int s = 4; s >= 1; s >>= 1)
        #pragma unroll
        for (int i = 0; i < s; ++i) t[i] = fmaxf(t[i], t[i + s]);
    float mx = fmaxf(t[0], __shfl_xor(t[0], 32));
    // defer-max (T13): only rescale when max grew by > 8
    if (__any(mx > mrun + 8.f)) {
        float mnew = fmaxf(mrun, mx);
        float scl = __expf(mrun - mnew);
        lrun *= scl;
        #pragma unroll
        for (int c = 0; c < 4; ++c)
            #pragma unroll
            for (int r = 0; r < 16; ++r) yv[c][r] *= scl;
        mrun = mnew;
    }
    float ps = 0.f;
    #pragma unroll
    for (int kf = 0; kf < KF; ++kf)
        #pragma unroll
        for (int r = 0; r < 16; ++r) {
            float p = __expf(qk[kf][r] - mrun);
            qk[kf][r] = p;
            ps += p;
        }
    ps += __shfl_xor(ps, 32);
    lrun += ps;
    // pack P to PV B-frags (16-key slices), cross-half exchange via shfl_xor(32)
    #pragma unroll
    for (int s = 0; s < 2 * KF; ++s) {
        const int kf = s >> 1;
        const int base = (s & 1) * 8;
        unsigned A0 = pkrtz(qk[kf][base + 0], qk[kf][base + 1]);
        unsigned A1 = pkrtz(qk[kf][base + 2], qk[kf][base + 3]);
        unsigned B0 = pkrtz(qk[kf][base + 4], qk[kf][base + 5]);
        unsigned B1 = pkrtz(qk[kf][base + 6], qk[kf][base + 7]);
        unsigned g0 = (unsigned)__shfl_xor((int)(hi ? A0 : B0), 32);
        unsigned g1 = (unsigned)__shfl_xor((int)(hi ? A1 : B1), 32);
        union { unsigned u[4]; f16x8 v; } fr;
        fr.u[0] = hi ? g0 : A0;
        fr.u[1] = hi ? g1 : A1;
        fr.u[2] = hi ? B0 : g0;
        fr.u[3] = hi ? B1 : g1;
        __builtin_amdgcn_s_setprio(1);
        #pragma unroll
        for (int c = 0; c < 4; ++c) {
            int row = c * 32 + lq;
            f16x8 gfr = *(const f16x8*)(Bg + row * 64 + ((s * 16 + hi * 8) ^ ((row & 7) << 3)));
            yv[c] = mfma32(gfr, fr.v, yv[c]);
        }
        __builtin_amdgcn_s_setprio(0);
    }
}

__global__ __launch_bounds__(256, 2) void k_attn(const f16* __restrict__ tpg, const f16* __restrict__ phi,
                                                 const f16* __restrict__ gx, f16* __restrict__ y) {
    int bid = blockIdx.x;                 // BB*98
    int b = bid / 98; int nt = bid % 98;
    int n0 = nt * 128;
    __shared__ f16 Bp[64 * 128];
    __shared__ f16 Bg[128 * 64];
    int tid = threadIdx.x;
    int wv = tid >> 6, ln = tid & 63, hi = ln >> 5, lq = ln & 31;
    // theta B-frags for this lane's q = n0 + wv*32 + lq (kept in regs)
    f16x8 bth[8];
    {
        const f16* rowp = tpg + ((size_t)b * NN + n0 + wv * 32 + lq) * 384;
        #pragma unroll
        for (int ks = 0; ks < 8; ++ks)
            bth[ks] = *(const f16x8*)(rowp + ks * 16 + hi * 8);
    }
    f32x16 yv[4];
    #pragma unroll
    for (int c = 0; c < 4; ++c)
        #pragma unroll
        for (int r = 0; r < 16; ++r) yv[c][r] = 0.f;
    float mrun = -1e30f, lrun = 0.f;
    const f16* phib = phi + (size_t)b * MM * CI;
    const f16* gb = gx + (size_t)b * CI * MM;

    f16x8 sp[4], sg[4];
    stage_load<64>(phib, gb, 0, tid, sp, sg);
    stage_write<64>(Bp, Bg, tid, sp, sg);
    __syncthreads();
    for (int t = 0; t < 23; ++t) {
        stage_load<64>(phib, gb, (t + 1) * 64, tid, sp, sg);
        attn_chunk<2>(Bp, Bg, bth, yv, mrun, lrun, lq, hi);
        __syncthreads();
        stage_write<64>(Bp, Bg, tid, sp, sg);
        __syncthreads();
    }
    stage_load<32>(phib, gb, 1536, tid, sp, sg);
    attn_chunk<2>(Bp, Bg, bth, yv, mrun, lrun, lq, hi);
    __syncthreads();
    stage_write<32>(Bp, Bg, tid, sp, sg);
    __syncthreads();
    attn_chunk<1>(Bp, Bg, bth, yv, mrun, lrun, lq, hi);

    // epilogue: y[n][ci] = yv/lrun ; regs 4k..4k+3 are ci-consecutive -> 8B stores
    float inv = 1.f / lrun;
    f16* yb = y + ((size_t)b * NN + n0 + wv * 32 + lq) * CI;
    #pragma unroll
    for (int c = 0; c < 4; ++c)
        #pragma unroll
        for (int k = 0; k < 4; ++k) {
            int ci = c * 32 + k * 8 + hi * 4;
            uint2 st;
            st.x = pkrtz(yv[c][4 * k + 0] * inv, yv[c][4 * k + 1] * inv);
            st.y = pkrtz(yv[c][4 * k + 2] * inv, yv[c][4 * k + 3] * inv);
            *(uint2*)(yb + ci) = st;
        }
}

// ---------------- K4: out = BN(wW @ y^T) + x ----------------
__global__ __launch_bounds__(256) void k_out(const f16* __restrict__ wWh, const f16* __restrict__ y,
                                             const float* __restrict__ x, const float* __restrict__ sc,
                                             const float* __restrict__ ofb, float* __restrict__ out) {
    int bid = blockIdx.x;                 // BB*196*2
    int b = bid / (196 * 2); int rem = bid % (196 * 2);
    int nt = rem >> 1, ct = rem & 1;
    int n0 = nt * 64, co0 = ct * 128;
    __shared__ f16 Ws[128 * 128];         // [co][ci] swizzled
    __shared__ f16 Ys[64 * 128];          // [n][ci] swizzled
    for (int s = threadIdx.x; s < 128 * 16; s += 256) {
        int row = s >> 4, sl = s & 15;
        f16x8 v = *(const f16x8*)(wWh + (size_t)(co0 + row) * CI + sl * 8);
        *(f16x8*)(Ws + row * 128 + ((sl * 8) ^ ((row & 7) << 3))) = v;
    }
    const f16* yb = y + (size_t)b * NN * CI + (size_t)n0 * CI;
    for (int s = threadIdx.x; s < 64 * 16; s += 256) {
        int row = s >> 4, sl = s & 15;
        f16x8 v = *(const f16x8*)(yb + (size_t)row * CI + sl * 8);
        *(f16x8*)(Ys + row * 128 + ((sl * 8) ^ ((row & 7) << 3))) = v;
    }
    __syncthreads();
    int wv = threadIdx.x >> 6, ln = threadIdx.x & 63;
    int wc = (wv >> 1) * 64, wn = (wv & 1) * 32;
    f32x4 acc[4][2];
    for (int i = 0; i < 4; ++i) for (int j = 0; j < 2; ++j)
        for (int r = 0; r < 4; ++r) acc[i][j][r] = 0.f;
    for (int kc = 0; kc < 4; ++kc) {
        int klo = kc * 32 + (ln >> 4) * 8;
        f16x8 afr[4], bfr[2];
        for (int i = 0; i < 4; ++i) {
            int rc = wc + i * 16 + (ln & 15);
            afr[i] = *(const f16x8*)(Ws + rc * 128 + (klo ^ ((rc & 7) << 3)));
        }
        for (int j = 0; j < 2; ++j) {
            int rn = wn + j * 16 + (ln & 15);
            bfr[j] = *(const f16x8*)(Ys + rn * 128 + (klo ^ ((rn & 7) << 3)));
        }
        for (int i = 0; i < 4; ++i)
            for (int j = 0; j < 2; ++j)
                acc[i][j] = mfma16(afr[i], bfr[j], acc[i][j]);
    }
    const float* xb = x + (size_t)b * CC * NN;
    float* ob = out + (size_t)b * CC * NN;
    for (int i = 0; i < 4; ++i)
        for (int j = 0; j < 2; ++j)
            for (int r = 0; r < 4; ++r) {
                int co = co0 + wc + i * 16 + (ln >> 4) * 4 + r;
                int n = n0 + wn + j * 16 + (ln & 15);
                size_t idx = (size_t)co * NN + n;
                ob[idx] = acc[i][j][r] * sc[co] + ofb[co] + xb[idx];
            }
}

extern "C" void kernel_launch(void* const* d_in, const int* in_sizes, int n_in,
                              void* d_out, int out_size, void* d_ws, size_t ws_size,
                              hipStream_t stream) {
    const float* x    = (const float*)d_in[0];
    const float* wg   = (const float*)d_in[1];
    const float* bg   = (const float*)d_in[2];
    const float* wth  = (const float*)d_in[3];
    const float* bth  = (const float*)d_in[4];
    const float* wph  = (const float*)d_in[5];
    const float* bph  = (const float*)d_in[6];
    const float* wW   = (const float*)d_in[7];
    const float* bW   = (const float*)d_in[8];
    const float* gam  = (const float*)d_in[9];
    const float* bet  = (const float*)d_in[10];
    const float* mean = (const float*)d_in[11];
    const float* var  = (const float*)d_in[12];
    if (ws_size < (size_t)WS_NEED) return;
    char* ws = (char*)d_ws;
    f16* w3t = (f16*)(ws + OFF_W3T);
    f16* wWh = (f16*)(ws + OFF_WWH);
    f16* b3  = (f16*)(ws + OFF_B3);
    float* sc  = (float*)(ws + OFF_SC);
    float* ofb = (float*)(ws + OFF_OFB);
    f16* xT  = (f16*)(ws + OFF_XT);
    f16* tpg = (f16*)(ws + OFF_TPG);
    f16* phi = (f16*)(ws + OFF_PHI);
    f16* gx  = (f16*)(ws + OFF_G);
    f16* yy  = (f16*)(ws + OFF_Y);
    float* out = (float*)d_out;

    k_prep<<<dim3(384), dim3(256), 0, stream>>>(wg, bg, wth, bth, wph, bph, wW, bW,
                                                gam, bet, mean, var, w3t, wWh, b3, sc, ofb);
    k_xt  <<<dim3(BB * 196 * 4), dim3(256), 0, stream>>>(x, xT);
    k_conv<<<dim3(BB * 98 * 3), dim3(256), 0, stream>>>(xT, w3t, b3, tpg);
    k_pool<<<dim3(BB * TP * HP), dim3(256), 0, stream>>>(tpg, phi, gx);
    k_attn<<<dim3(BB * 98), dim3(256), 0, stream>>>(tpg, phi, gx, yy);
    k_out <<<dim3(BB * 196 * 2), dim3(256), 0, stream>>>(wWh, yy, x, sc, ofb, out);
}